// Round 1
// baseline (19.231 us; speedup 1.0000x reference)
//
#include <hip/hip_runtime.h>
#include <math.h>

// VolumeRenderer: B rays x MAX_STEPS raymarch over a DEPTH=2, N=2 octree.
// Problem constants (fixed by the reference source):
constexpr int   N_      = 2;
constexpr int   DEPTH   = 2;
constexpr int   DATA_DIM = 28;
constexpr int   MAX_STEPS = 16;
constexpr float STEP_SIZE = 0.001f;
constexpr float BG = 1.0f;
constexpr int   N_NODES = 1 + N_*N_*N_;       // 9
constexpr int   CELLS   = N_*N_*N_;           // 8
constexpr int   ENTRY_F = DATA_DIM;           // 28 floats per (node,cell)
constexpr int   DATA_FLOATS = N_NODES * CELLS * ENTRY_F;  // 2016 (8064 B)
constexpr int   CHILD_INTS  = N_NODES * CELLS;            // 72

__device__ __forceinline__ void dda_unit(float cx, float cy, float cz,
                                         float ix, float iy, float iz,
                                         float& tmin, float& tmax) {
    float t1x = -cx * ix, t2x = t1x + ix;
    float t1y = -cy * iy, t2y = t1y + iy;
    float t1z = -cz * iz, t2z = t1z + iz;
    float mn = fmaxf(fmaxf(fminf(t1x, t2x), fminf(t1y, t2y)), fminf(t1z, t2z));
    float mx = fminf(fminf(fmaxf(t1x, t2x), fmaxf(t1y, t2y)), fmaxf(t1z, t2z));
    tmin = fmaxf(mn, 0.0f);
    tmax = fminf(mx, 1000000000.0f);
}

__global__ __launch_bounds__(256) void vr_kernel(
    const float* __restrict__ origins,
    const float* __restrict__ dirs,
    const float* __restrict__ viewdirs,
    const float* __restrict__ data,
    const int*   __restrict__ child,
    const float* __restrict__ offset,
    const float* __restrict__ invradius_p,
    float* __restrict__ out,
    int B)
{
    __shared__ float s_data[DATA_FLOATS];
    __shared__ int   s_child[CHILD_INTS];
    for (int i = threadIdx.x; i < DATA_FLOATS; i += blockDim.x) s_data[i] = data[i];
    for (int i = threadIdx.x; i < CHILD_INTS;  i += blockDim.x) s_child[i] = child[i];
    __syncthreads();

    int tid = blockIdx.x * blockDim.x + threadIdx.x;
    if (tid >= B) return;

    float ox = origins[tid*3+0], oy = origins[tid*3+1], oz = origins[tid*3+2];
    float dx = dirs[tid*3+0],    dy = dirs[tid*3+1],    dz = dirs[tid*3+2];
    float vx = viewdirs[tid*3+0],vy = viewdirs[tid*3+1],vz = viewdirs[tid*3+2];
    float invr = invradius_p[0];
    float otx = offset[0] + ox * invr;
    float oty = offset[1] + oy * invr;
    float otz = offset[2] + oz * invr;

    // SH-9 basis from viewdirs
    float sh[9];
    {
        const float C0 = 0.28209479177387814f;
        const float C1 = 0.4886025119029199f;
        sh[0] = C0;
        sh[1] = -C1 * vy;
        sh[2] =  C1 * vz;
        sh[3] = -C1 * vx;
        sh[4] =  1.0925484305920792f * vx * vy;
        sh[5] = -1.0925484305920792f * vy * vz;
        sh[6] =  0.31539156525252005f * (2.0f*vz*vz - vx*vx - vy*vy);
        sh[7] = -1.0925484305920792f * vx * vz;
        sh[8] =  0.5462742152960396f * (vx*vx - vy*vy);
    }

    float nrm = sqrtf(dx*dx + dy*dy + dz*dz);
    float dnx = dx / nrm, dny = dy / nrm, dnz = dz / nrm;
    float ivx = 1.0f / (dnx + 1e-9f);
    float ivy = 1.0f / (dny + 1e-9f);
    float ivz = 1.0f / (dnz + 1e-9f);

    float t, tmax;
    dda_unit(otx, oty, otz, ivx, ivy, ivz, t, tmax);

    float delta_scale = 1.0f / invr;
    float light = 1.0f;
    float o0 = 0.0f, o1 = 0.0f, o2 = 0.0f;

    for (int step = 0; step < MAX_STEPS; ++step) {
        if (!(t < tmax)) break;   // inactive rays never reactivate (t frozen)

        float px = otx + t * dnx;
        float py = oty + t * dny;
        float pz = otz + t * dnz;
        float cx = fminf(fmaxf(px, 0.0f), 1.0f - 1e-6f);
        float cy = fminf(fmaxf(py, 0.0f), 1.0f - 1e-6f);
        float cz = fminf(fmaxf(pz, 0.0f), 1.0f - 1e-6f);

        // ---- tree_query (DEPTH levels) ----
        int   node = 0;
        float curx = cx, cury = cy, curz = cz;
        float cornx = 0.f, corny = 0.f, cornz = 0.f;
        float length = 1.0f;
        bool  done = false;
        int   fentry = 0;  // (node*CELLS + cell) of the entry providing val
        #pragma unroll
        for (int d = 0; d < DEPTH; ++d) {
            if (!done) {
                int ix = min(max((int)floorf(curx * (float)N_), 0), N_ - 1);
                int iy = min(max((int)floorf(cury * (float)N_), 0), N_ - 1);
                int iz = min(max((int)floorf(curz * (float)N_), 0), N_ - 1);
                int cell = (ix * N_ + iy) * N_ + iz;
                int e = node * CELLS + cell;
                int ch = s_child[e];
                fentry = e;
                float newlen = length * 0.5f;
                cornx += (float)ix * newlen;
                corny += (float)iy * newlen;
                cornz += (float)iz * newlen;
                curx = curx * (float)N_ - (float)ix;
                cury = cury * (float)N_ - (float)iy;
                curz = curz * (float)N_ - (float)iz;
                length = newlen;
                node += ch;
                done = (ch == 0);
            }
        }

        // load the 28-float entry as 7x float4 (ds_read_b128)
        float v[28];
        {
            const float4* e4 = reinterpret_cast<const float4*>(&s_data[fentry * ENTRY_F]);
            #pragma unroll
            for (int q = 0; q < 7; ++q) {
                float4 w = e4[q];
                v[q*4+0] = w.x; v[q*4+1] = w.y; v[q*4+2] = w.z; v[q*4+3] = w.w;
            }
        }

        float invlen = 1.0f / length;
        float plx = (px - cornx) * invlen;
        float ply = (py - corny) * invlen;
        float plz = (pz - cornz) * invlen;
        float smin, smax;
        dda_unit(plx, ply, plz, ivx, ivy, ivz, smin, smax);
        float delta_t = (smax - smin) * length + STEP_SIZE;

        float sigma = fmaxf(v[27], 0.0f);
        float att = expf(-delta_t * sigma * delta_scale);
        float weight = light * (1.0f - att);

        // rgb = sigmoid(sh . v[c*9 .. c*9+8])
        float rgb[3];
        #pragma unroll
        for (int c = 0; c < 3; ++c) {
            float acc = 0.0f;
            #pragma unroll
            for (int k = 0; k < 9; ++k) acc += sh[k] * v[c * 9 + k];
            rgb[c] = 1.0f / (1.0f + expf(-acc));
        }

        o0 += weight * rgb[0];
        o1 += weight * rgb[1];
        o2 += weight * rgb[2];
        light *= att;
        t += delta_t;
    }

    out[tid*3+0] = o0 + light * BG;
    out[tid*3+1] = o1 + light * BG;
    out[tid*3+2] = o2 + light * BG;
}

extern "C" void kernel_launch(void* const* d_in, const int* in_sizes, int n_in,
                              void* d_out, int out_size, void* d_ws, size_t ws_size,
                              hipStream_t stream) {
    const float* origins  = (const float*)d_in[0];
    const float* dirs     = (const float*)d_in[1];
    const float* viewdirs = (const float*)d_in[2];
    const float* data     = (const float*)d_in[3];
    const int*   child    = (const int*)d_in[4];
    const float* offset   = (const float*)d_in[5];
    const float* invrad   = (const float*)d_in[6];
    float* out = (float*)d_out;
    int B = in_sizes[0] / 3;
    int block = 256;
    int grid = (B + block - 1) / block;
    vr_kernel<<<grid, block, 0, stream>>>(origins, dirs, viewdirs, data, child,
                                          offset, invrad, out, B);
}

// Round 2
// 13.619 us; speedup vs baseline: 1.4120x; 1.4120x over previous
//
#include <hip/hip_runtime.h>
#include <math.h>

typedef _Float16 f16;
typedef _Float16 f16x2 __attribute__((ext_vector_type(2)));

constexpr int   DATA_DIM  = 28;
constexpr int   MAX_STEPS = 16;
constexpr float STEP_SIZE = 0.001f;
constexpr float BG        = 1.0f;
constexpr int   CELLS     = 8;     // N^3
constexpr int   NVOX      = 64;    // (N^DEPTH)^3 = 4^3
constexpr int   VOX_H     = 28;    // halves per voxel record (56 B)

// fp16 pair dot with f32 accumulate; falls back to scalar if builtin missing.
__device__ __forceinline__ float fdot2(unsigned w, f16x2 s, float acc) {
#if __has_builtin(__builtin_amdgcn_fdot2)
    return __builtin_amdgcn_fdot2(__builtin_bit_cast(f16x2, w), s, acc, false);
#else
    f16x2 a = __builtin_bit_cast(f16x2, w);
    return acc + (float)a.x * (float)s.x + (float)a.y * (float)s.y;
#endif
}

__global__ __launch_bounds__(256) void vr_kernel(
    const float* __restrict__ origins,
    const float* __restrict__ dirs,
    const float* __restrict__ viewdirs,
    const float* __restrict__ data,
    const int*   __restrict__ child,
    const float* __restrict__ offset,
    const float* __restrict__ invradius_p,
    float* __restrict__ out,
    int B)
{
    // Per-voxel (res-4) LUT: fp16 data record + cell length. The traversal
    // result is constant within each res-4 voxel, so precompute it once.
    __shared__ f16   s_vh[NVOX * VOX_H];   // 3584 B, stride 56 B (16 b64 groups)
    __shared__ float s_len[NVOX];
    __shared__ int   s_fent[NVOX];

    const int t0 = threadIdx.x;
    if (t0 < NVOX) {
        int vx = t0 >> 4, vy = (t0 >> 2) & 3, vz = t0 & 3;
        // depth-0 descent
        int e  = ((vx >> 1) * 2 + (vy >> 1)) * 2 + (vz >> 1);   // node 0
        int ch = child[e];
        int   fe  = e;
        float len = 0.5f;
        if (ch != 0) {              // depth-1 descent
            int node = ch;          // node 0 + ch
            e  = node * CELLS + ((vx & 1) * 2 + (vy & 1)) * 2 + (vz & 1);
            fe  = e;
            len = 0.25f;
        }
        s_fent[t0] = fe;
        s_len[t0]  = len;
    }
    __syncthreads();
    // stage fp16 voxel records (1792 halves = 7 iters of 256 threads)
    for (int i = t0; i < NVOX * VOX_H; i += 256) {
        int v = i / VOX_H;
        int j = i - v * VOX_H;
        s_vh[i] = (f16)data[s_fent[v] * DATA_DIM + j];
    }
    __syncthreads();

    int tid = blockIdx.x * 256 + t0;
    if (tid >= B) return;

    float ox = origins[tid*3+0], oy = origins[tid*3+1], oz = origins[tid*3+2];
    float dx = dirs[tid*3+0],    dy = dirs[tid*3+1],    dz = dirs[tid*3+2];
    float vdx = viewdirs[tid*3+0], vdy = viewdirs[tid*3+1], vdz = viewdirs[tid*3+2];
    float invr = invradius_p[0];
    float otx = offset[0] + ox * invr;
    float oty = offset[1] + oy * invr;
    float otz = offset[2] + oz * invr;

    // SH-9 basis, packed as fp16 pairs in two alignments:
    // shA = (s0,s1)(s2,s3)(s4,s5)(s6,s7)(s8,0)  — even-half start (c=0, c=2)
    // shB = (0,s0)(s1,s2)(s3,s4)(s5,s6)(s7,s8)  — odd-half start  (c=1)
    float sh[9];
    {
        const float C0 = 0.28209479177387814f;
        const float C1 = 0.4886025119029199f;
        sh[0] = C0;
        sh[1] = -C1 * vdy;
        sh[2] =  C1 * vdz;
        sh[3] = -C1 * vdx;
        sh[4] =  1.0925484305920792f * vdx * vdy;
        sh[5] = -1.0925484305920792f * vdy * vdz;
        sh[6] =  0.31539156525252005f * (2.0f*vdz*vdz - vdx*vdx - vdy*vdy);
        sh[7] = -1.0925484305920792f * vdx * vdz;
        sh[8] =  0.5462742152960396f * (vdx*vdx - vdy*vdy);
    }
    f16x2 shA[5], shB[5];
    shA[0] = f16x2{(f16)sh[0], (f16)sh[1]};
    shA[1] = f16x2{(f16)sh[2], (f16)sh[3]};
    shA[2] = f16x2{(f16)sh[4], (f16)sh[5]};
    shA[3] = f16x2{(f16)sh[6], (f16)sh[7]};
    shA[4] = f16x2{(f16)sh[8], (f16)0.0f};
    shB[0] = f16x2{(f16)0.0f,  (f16)sh[0]};
    shB[1] = f16x2{(f16)sh[1], (f16)sh[2]};
    shB[2] = f16x2{(f16)sh[3], (f16)sh[4]};
    shB[3] = f16x2{(f16)sh[5], (f16)sh[6]};
    shB[4] = f16x2{(f16)sh[7], (f16)sh[8]};

    // Direction normalization / invdirs: keep IEEE-precise (once per ray;
    // these feed the t<tmax decisions).
    float nrm = sqrtf(dx*dx + dy*dy + dz*dz);
    float dnx = dx / nrm, dny = dy / nrm, dnz = dz / nrm;
    float ivx = 1.0f / (dnx + 1e-9f);
    float ivy = 1.0f / (dny + 1e-9f);
    float ivz = 1.0f / (dnz + 1e-9f);

    float t, tmax;
    {
        float t1x = -otx * ivx, t2x = t1x + ivx;
        float t1y = -oty * ivy, t2y = t1y + ivy;
        float t1z = -otz * ivz, t2z = t1z + ivz;
        float mn = fmaxf(fmaxf(fminf(t1x,t2x), fminf(t1y,t2y)), fminf(t1z,t2z));
        float mx = fminf(fminf(fmaxf(t1x,t2x), fmaxf(t1y,t2y)), fmaxf(t1z,t2z));
        t    = fmaxf(mn, 0.0f);
        tmax = fminf(mx, 1000000000.0f);
    }

    const float katt = -(1.0f / invr);   // -delta_scale
    float light = 1.0f;
    float o0 = 0.0f, o1 = 0.0f, o2 = 0.0f;

    #pragma unroll 1
    for (int s = 0; s < MAX_STEPS; ++s) {
        if (!(t < tmax)) break;   // inactive rays never reactivate

        float px = fmaf(t, dnx, otx);
        float py = fmaf(t, dny, oty);
        float pz = fmaf(t, dnz, otz);
        float pcx = fminf(fmaxf(px, 0.0f), 0.999999f);
        float pcy = fminf(fmaxf(py, 0.0f), 0.999999f);
        float pcz = fminf(fmaxf(pz, 0.0f), 0.999999f);

        int vx = (int)(pcx * 4.0f);
        int vy = (int)(pcy * 4.0f);
        int vz = (int)(pcz * 4.0f);
        int lidx = (vx << 4) + (vy << 2) + vz;

        float len    = s_len[lidx];
        float invlen = __builtin_amdgcn_rcpf(len);   // exact: len is 2^-k

        // corner from clamped pos (== traversal corner); local pos from raw pos
        float cfx = floorf(pcx * invlen);
        float cfy = floorf(pcy * invlen);
        float cfz = floorf(pcz * invlen);
        float plx = fmaf(px, invlen, -cfx);
        float ply = fmaf(py, invlen, -cfy);
        float plz = fmaf(pz, invlen, -cfz);

        float t1x = -plx * ivx, t2x = t1x + ivx;
        float t1y = -ply * ivy, t2y = t1y + ivy;
        float t1z = -plz * ivz, t2z = t1z + ivz;
        float mn = fmaxf(fmaxf(fminf(t1x,t2x), fminf(t1y,t2y)), fminf(t1z,t2z));
        float mx = fminf(fminf(fmaxf(t1x,t2x), fmaxf(t1y,t2y)), fmaxf(t1z,t2z));
        float smin = fmaxf(mn, 0.0f);
        float smax = fminf(mx, 1000000000.0f);
        float dt = fmaf(smax - smin, len, STEP_SIZE);

        // voxel record: 14 dwords (28 fp16), 7x ds_read_b64
        const uint2* rec = (const uint2*)(s_vh + lidx * VOX_H);
        uint2 q0 = rec[0], q1 = rec[1], q2 = rec[2], q3 = rec[3];
        uint2 q4 = rec[4], q5 = rec[5], q6 = rec[6];
        // dwords: D0..D13
        unsigned D0=q0.x, D1=q0.y, D2=q1.x, D3=q1.y, D4=q2.x, D5=q2.y, D6=q3.x;
        unsigned D7=q3.y, D8=q4.x, D9=q4.y, D10=q5.x, D11=q5.y, D12=q6.x, D13=q6.y;

        // channel dots (v_dot2_f32_f16)
        float a0 = 0.0f, a1 = 0.0f, a2 = 0.0f;
        a0 = fdot2(D0, shA[0], a0); a0 = fdot2(D1, shA[1], a0);
        a0 = fdot2(D2, shA[2], a0); a0 = fdot2(D3, shA[3], a0);
        a0 = fdot2(D4, shA[4], a0);
        a1 = fdot2(D4, shB[0], a1); a1 = fdot2(D5, shB[1], a1);
        a1 = fdot2(D6, shB[2], a1); a1 = fdot2(D7, shB[3], a1);
        a1 = fdot2(D8, shB[4], a1);
        a2 = fdot2(D9, shA[0], a2); a2 = fdot2(D10, shA[1], a2);
        a2 = fdot2(D11, shA[2], a2); a2 = fdot2(D12, shA[3], a2);
        a2 = fdot2(D13, shA[4], a2);

        f16x2 last = __builtin_bit_cast(f16x2, D13);
        float sigma = fmaxf((float)last.y, 0.0f);

        float att    = __expf(katt * dt * sigma);
        float weight = light * (1.0f - att);

        float r0 = __builtin_amdgcn_rcpf(1.0f + __expf(-a0));
        float r1 = __builtin_amdgcn_rcpf(1.0f + __expf(-a1));
        float r2 = __builtin_amdgcn_rcpf(1.0f + __expf(-a2));

        o0 = fmaf(weight, r0, o0);
        o1 = fmaf(weight, r1, o1);
        o2 = fmaf(weight, r2, o2);
        light *= att;
        t += dt;
    }

    out[tid*3+0] = fmaf(light, BG, o0);
    out[tid*3+1] = fmaf(light, BG, o1);
    out[tid*3+2] = fmaf(light, BG, o2);
}

extern "C" void kernel_launch(void* const* d_in, const int* in_sizes, int n_in,
                              void* d_out, int out_size, void* d_ws, size_t ws_size,
                              hipStream_t stream) {
    const float* origins  = (const float*)d_in[0];
    const float* dirs     = (const float*)d_in[1];
    const float* viewdirs = (const float*)d_in[2];
    const float* data     = (const float*)d_in[3];
    const int*   child    = (const int*)d_in[4];
    const float* offset   = (const float*)d_in[5];
    const float* invrad   = (const float*)d_in[6];
    float* out = (float*)d_out;
    int B = in_sizes[0] / 3;
    int block = 256;
    int grid = (B + block - 1) / block;
    vr_kernel<<<grid, block, 0, stream>>>(origins, dirs, viewdirs, data, child,
                                          offset, invrad, out, B);
}